// Round 1
// baseline (225.583 us; speedup 1.0000x reference)
//
#include <hip/hip_runtime.h>
#include <stdint.h>

typedef unsigned short u16;
typedef unsigned int u32;
using f32x4 = __attribute__((ext_vector_type(4))) float;
using bf16x8 = __attribute__((ext_vector_type(8))) short;
using u16x8 = __attribute__((ext_vector_type(8))) unsigned short;
using u16x4 = __attribute__((ext_vector_type(4))) unsigned short;

__device__ __forceinline__ u16 f2bf(float f) {
  u32 u = __float_as_uint(f);
  u32 r = (u + 0x7FFFu + ((u >> 16) & 1u)) >> 16;  // RNE
  return (u16)r;
}
__device__ __forceinline__ float bf2f(u16 h) { return __uint_as_float(((u32)h) << 16); }

__device__ __forceinline__ void gload16(const void* g, void* l) {
  __builtin_amdgcn_global_load_lds((const __attribute__((address_space(1))) void*)g,
                                   (__attribute__((address_space(3))) void*)l, 16, 0, 0);
}

// ---------------- fp32 -> bf16 convert ----------------
__global__ __launch_bounds__(256) void cvt_kernel(const float* __restrict__ src,
                                                  u16* __restrict__ dst, int n4) {
  int i = blockIdx.x * 256 + threadIdx.x;
  if (i < n4) {
    const float4 f = ((const float4*)src)[i];
    u16x4 o;
    o[0] = f2bf(f.x); o[1] = f2bf(f.y); o[2] = f2bf(f.z); o[3] = f2bf(f.w);
    ((u16x4*)dst)[i] = o;
  }
}

// ---------------- 128x128 bf16 GEMM, C = A * B^T (both row-major [rows][K]) ----------------
// MODE 0: epilogue scatters qkv into q[B,H,N,64], k[B,H,N,64], vT[B,H,64,N] (bf16)
// MODE 1: epilogue writes fp32 out[M][N] += bias[n]
template <int MODE, int Mdim, int Ndim, int Kdim>
__global__ __launch_bounds__(256) void gemm_bt(const u16* __restrict__ A, const u16* __restrict__ Bw,
                                               u16* __restrict__ qb, u16* __restrict__ kb,
                                               u16* __restrict__ vTb,
                                               float* __restrict__ out, const float* __restrict__ bias) {
  __shared__ __align__(16) u16 lA[128 * 32];
  __shared__ __align__(16) u16 lB[128 * 32];
  const int tid = threadIdx.x;
  const int wid = tid >> 6, lane = tid & 63;
  const int m0 = blockIdx.x * 128, n0 = blockIdx.y * 128;
  const int wm = (wid >> 1) * 64, wn = (wid & 1) * 64;
  const int g = lane >> 4, r16 = lane & 15;

  f32x4 acc[4][4] = {};

  const int srow = wid * 16 + (lane >> 2);
  const int scol = (lane & 3) * 8;
  const u16* gA = A + (size_t)(m0 + srow) * Kdim + scol;
  const u16* gB = Bw + (size_t)(n0 + srow) * Kdim + scol;
  u16* lAw = lA + wid * 512;
  u16* lBw = lB + wid * 512;

  for (int k0 = 0; k0 < Kdim; k0 += 32) {
    gload16(gA + k0, lAw);
    gload16(gA + (size_t)64 * Kdim + k0, lAw + 2048);
    gload16(gB + k0, lBw);
    gload16(gB + (size_t)64 * Kdim + k0, lBw + 2048);
    __syncthreads();
    bf16x8 af[4], bfr[4];
#pragma unroll
    for (int i = 0; i < 4; ++i) af[i] = *(const bf16x8*)(lA + (wm + i * 16 + r16) * 32 + g * 8);
#pragma unroll
    for (int j = 0; j < 4; ++j) bfr[j] = *(const bf16x8*)(lB + (wn + j * 16 + r16) * 32 + g * 8);
#pragma unroll
    for (int i = 0; i < 4; ++i)
#pragma unroll
      for (int j = 0; j < 4; ++j)
        acc[i][j] = __builtin_amdgcn_mfma_f32_16x16x32_bf16(af[i], bfr[j], acc[i][j], 0, 0, 0);
    __syncthreads();
  }

#pragma unroll
  for (int i = 0; i < 4; ++i) {
    const int gm = m0 + wm + i * 16 + g * 4;  // multiple of 4
#pragma unroll
    for (int j = 0; j < 4; ++j) {
      const int gn = n0 + wn + j * 16 + r16;
      if constexpr (MODE == 1) {
        const float bv = bias[gn];
#pragma unroll
        for (int r = 0; r < 4; ++r) out[(size_t)(gm + r) * Ndim + gn] = acc[i][j][r] + bv;
      } else {
        const int t = gn / 768;
        const int rem = gn - t * 768;
        const int h = rem >> 6, d = rem & 63;
        if (t == 2) {
          // vT[b*12+h][d][n], 4 consecutive n -> one 8B store
          u16x4 pk;
#pragma unroll
          for (int r = 0; r < 4; ++r) pk[r] = f2bf(acc[i][j][r]);
          const int b = gm >> 10, n = gm & 1023;
          *(u16x4*)(vTb + ((size_t)((b * 12 + h) * 64 + d)) * 1024 + n) = pk;
        } else {
          u16* dst = (t == 0) ? qb : kb;
#pragma unroll
          for (int r = 0; r < 4; ++r) {
            const int b = (gm + r) >> 10, n = (gm + r) & 1023;
            dst[((size_t)((b * 12 + h) * 1024 + n)) * 64 + d] = f2bf(acc[i][j][r]);
          }
        }
      }
    }
  }
}

// ---------------- per-(b,h) mean of v over tokens ----------------
__global__ __launch_bounds__(256) void vmean_kernel(const u16* __restrict__ vTb,
                                                    float* __restrict__ vmean) {
  const int bh = blockIdx.x, t = threadIdx.x;
  const int d = t >> 2, part = t & 3;
  const u16* src = vTb + ((size_t)bh * 64 + d) * 1024 + part * 256;
  float s = 0.f;
  for (int j = 0; j < 256; j += 8) {
    u16x8 u = *(const u16x8*)(src + j);
#pragma unroll
    for (int e = 0; e < 8; ++e) s += bf2f(u[e]);
  }
  s += __shfl_xor(s, 1);
  s += __shfl_xor(s, 2);
  if (part == 0) vmean[bh * 64 + d] = s * (1.0f / 1024.0f);
}

// ---------------- masked attention, 3 branches ----------------
// grid: (rt=16, bh=96, br=3); 4 waves x 16 rows = 64 rows/block; 32-key chunks.
__global__ __launch_bounds__(256) void attn_kernel(const u16* __restrict__ qg, const u16* __restrict__ kg,
                                                   const u16* __restrict__ vg, const float* __restrict__ vmean,
                                                   u16* __restrict__ og) {
  __shared__ __align__(16) u16 lK[32 * 64];      // [key][hd], hd 16B-chunks XOR-swizzled by (key&7)
  __shared__ __align__(16) u16 lV[64 * 32];      // [d][key],  key 16B-chunks XOR-swizzled by (d&3)
  __shared__ __align__(16) u16 lP[4][16 * 40];   // per-wave P tile, 80B row stride (conflict-free)

  const int rt = blockIdx.x;
  const int bh = blockIdx.y;
  const int br = blockIdx.z;
  const int tid = threadIdx.x;
  const int wid = tid >> 6, lane = tid & 63;
  const int g = lane >> 4, r16 = lane & 15;
  const int row0 = rt * 64 + wid * 16;

  const int nchunk = (br == 0) ? (rt == 0 ? 1 : 0) : ((br == 1) ? 32 : (rt == 0 ? 32 : 1));

  // q fragments (A-operand): row = r16, hd = s*32 + g*8 + i
  const u16* qrow = qg + ((size_t)bh * 1024 + row0 + r16) * 64;
  const bf16x8 aq0 = *(const bf16x8*)(qrow + g * 8);
  const bf16x8 aq1 = *(const bf16x8*)(qrow + 32 + g * 8);

  // staging coords (pre-swizzled global source -> linear LDS dest)
  const int kr = wid * 8 + (lane >> 3);
  const int kc = ((lane & 7) ^ (kr & 7)) * 8;
  const u16* gK = kg + (size_t)bh * 65536;
  const int vr = wid * 16 + (lane >> 2);
  const int vc = ((lane & 3) ^ (vr & 3)) * 8;
  const u16* gV = vg + (size_t)bh * 65536 + (size_t)vr * 1024 + vc;

  f32x4 oa[4] = {};
  float lsum[4] = {0.f, 0.f, 0.f, 0.f};
  u16* lPw = lP[wid];

  for (int c = 0; c < nchunk; ++c) {
    gload16(gK + (size_t)(c * 32 + kr) * 64 + kc, lK + wid * 512);
    gload16(gV + c * 32, lV + wid * 512);
    __syncthreads();

    bool active;
    if (br == 0) active = (wid == 0);
    else if (br == 1) active = true;
    else active = (c == 0) || (rt == 0 && wid == 0);

    if (active) {
      f32x4 sa[2] = {};
#pragma unroll
      for (int js = 0; js < 2; ++js) {
        const int krow = js * 16 + r16;
        const bf16x8 bk0 = *(const bf16x8*)(lK + krow * 64 + ((g ^ (krow & 7)) * 8));
        const bf16x8 bk1 = *(const bf16x8*)(lK + krow * 64 + (((4 + g) ^ (krow & 7)) * 8));
        sa[js] = __builtin_amdgcn_mfma_f32_16x16x32_bf16(aq0, bk0, sa[js], 0, 0, 0);
        sa[js] = __builtin_amdgcn_mfma_f32_16x16x32_bf16(aq1, bk1, sa[js], 0, 0, 0);
      }
#pragma unroll
      for (int js = 0; js < 2; ++js) {
        const int key = c * 32 + js * 16 + r16;
#pragma unroll
        for (int r = 0; r < 4; ++r) {
          const int irow = row0 + g * 4 + r;
          bool m;
          if (br == 0) m = (irow < 9) && (key < 9);
          else if (br == 1) m = ((irow == 0) || (irow >= 9)) && ((key == 0) || (key >= 9));
          else m = (irow >= 9) ? (key < 9) : ((irow == 0) ? ((key == 0) || (key >= 9)) : (key >= 9));
          const float p = m ? __expf(sa[js][r] * 0.125f) : 0.f;
          lsum[r] += p;
          lPw[(g * 4 + r) * 40 + js * 16 + r16] = f2bf(p);
        }
      }
      const bf16x8 ap = *(const bf16x8*)(lPw + r16 * 40 + g * 8);
#pragma unroll
      for (int jt = 0; jt < 4; ++jt) {
        const int drow = jt * 16 + r16;
        const bf16x8 bv = *(const bf16x8*)(lV + drow * 32 + ((g ^ (drow & 3)) * 8));
        oa[jt] = __builtin_amdgcn_mfma_f32_16x16x32_bf16(ap, bv, oa[jt], 0, 0, 0);
      }
    }
    __syncthreads();
  }

  // row sums: reduce across the 16 lanes (cols) of each g-group
#pragma unroll
  for (int r = 0; r < 4; ++r) {
    float s = lsum[r];
    s += __shfl_xor(s, 1); s += __shfl_xor(s, 2); s += __shfl_xor(s, 4); s += __shfl_xor(s, 8);
    lsum[r] = s;
  }
  const int b = bh / 12, h = bh - b * 12;
#pragma unroll
  for (int r = 0; r < 4; ++r) {
    const int irow = row0 + g * 4 + r;
    const bool fullrow = (br == 0) ? (irow >= 9) : ((br == 1) ? (irow >= 1 && irow < 9) : false);
    const float inv = fullrow ? 0.f : 1.0f / lsum[r];
#pragma unroll
    for (int jt = 0; jt < 4; ++jt) {
      const int d = jt * 16 + r16;
      const float v = fullrow ? vmean[bh * 64 + d] : oa[jt][r] * inv;
      og[((size_t)(br * 8192 + b * 1024 + irow)) * 768 + h * 64 + d] = f2bf(v);
    }
  }
}

// ---------------- host launcher ----------------
extern "C" void kernel_launch(void* const* d_in, const int* in_sizes, int n_in,
                              void* d_out, int out_size, void* d_ws, size_t ws_size,
                              hipStream_t stream) {
  (void)in_sizes; (void)n_in; (void)out_size; (void)ws_size;
  const float* x      = (const float*)d_in[0];
  const float* w_qkv  = (const float*)d_in[1];
  const float* w_proj = (const float*)d_in[2];
  const float* b_proj = (const float*)d_in[3];

  char* ws = (char*)d_ws;
  u16* xb     = (u16*)(ws + 0);           // 8192*768        bf16 = 12,582,912 B
  u16* wqkvb  = (u16*)(ws + 12582912);    // 2304*768        bf16 =  3,538,944 B
  u16* wprojb = (u16*)(ws + 16121856);    // 768*768         bf16 =  1,179,648 B
  u16* qb     = (u16*)(ws + 17301504);    // 96*1024*64      bf16 = 12,582,912 B
  u16* kb     = (u16*)(ws + 29884416);    // 96*1024*64      bf16 = 12,582,912 B
  u16* vTb    = (u16*)(ws + 42467328);    // 96*64*1024      bf16 = 12,582,912 B
  float* vmn  = (float*)(ws + 55050240);  // 96*64           f32  =     24,576 B
  u16* ob     = (u16*)(ws + 55074816);    // 3*8192*768      bf16 = 37,748,736 B  (end ~92.8MB)

  cvt_kernel<<<6144, 256, 0, stream>>>(x, xb, 1572864);
  cvt_kernel<<<1728, 256, 0, stream>>>(w_qkv, wqkvb, 442368);
  cvt_kernel<<<576, 256, 0, stream>>>(w_proj, wprojb, 147456);

  gemm_bt<0, 8192, 2304, 768><<<dim3(64, 18), 256, 0, stream>>>(
      xb, wqkvb, qb, kb, vTb, nullptr, nullptr);

  vmean_kernel<<<96, 256, 0, stream>>>(vTb, vmn);

  attn_kernel<<<dim3(16, 96, 3), 256, 0, stream>>>(qb, kb, vTb, vmn, ob);

  gemm_bt<1, 24576, 768, 768><<<dim3(192, 6), 256, 0, stream>>>(
      ob, wprojb, nullptr, nullptr, nullptr, (float*)d_out, b_proj);
}

// Round 5
// 194.403 us; speedup vs baseline: 1.1604x; 1.1604x over previous
//
#include <hip/hip_runtime.h>
#include <stdint.h>

typedef unsigned short u16;
typedef unsigned int u32;
using f32x4 = __attribute__((ext_vector_type(4))) float;
using bf16x8 = __attribute__((ext_vector_type(8))) short;
using u16x8 = __attribute__((ext_vector_type(8))) unsigned short;
using u16x4 = __attribute__((ext_vector_type(4))) unsigned short;

#define QSCALE 0.18033688f  // 0.125 * log2(e): scores in exp2 domain

__device__ __forceinline__ u16 f2bf(float f) {
  u32 u = __float_as_uint(f);
  u32 r = (u + 0x7FFFu + ((u >> 16) & 1u)) >> 16;  // RNE
  return (u16)r;
}
__device__ __forceinline__ float bf2f(u16 h) { return __uint_as_float(((u32)h) << 16); }

__device__ __forceinline__ void gload16(const void* g, void* l) {
  __builtin_amdgcn_global_load_lds((const __attribute__((address_space(1))) void*)g,
                                   (__attribute__((address_space(3))) void*)l, 16, 0, 0);
}

// ---------------- fp32 -> bf16 convert ----------------
__global__ __launch_bounds__(256) void cvt_kernel(const float* __restrict__ src,
                                                  u16* __restrict__ dst, int n4) {
  int i = blockIdx.x * 256 + threadIdx.x;
  if (i < n4) {
    const float4 f = ((const float4*)src)[i];
    u16x4 o;
    o[0] = f2bf(f.x); o[1] = f2bf(f.y); o[2] = f2bf(f.z); o[3] = f2bf(f.w);
    ((u16x4*)dst)[i] = o;
  }
}

// ---------------- 128x128 bf16 GEMM, C = A * B^T (both row-major [rows][K]) ----------------
// MODE 0: epilogue scatters qkv into q[B,H,N,64] (pre-scaled by QSCALE), k[B,H,N,64], vT[B,H,64,N]
// MODE 1: epilogue writes fp32 out[M][N] += bias[n]
template <int MODE, int Mdim, int Ndim, int Kdim>
__global__ __launch_bounds__(256) void gemm_bt(const u16* __restrict__ A, const u16* __restrict__ Bw,
                                               u16* __restrict__ qb, u16* __restrict__ kb,
                                               u16* __restrict__ vTb,
                                               float* __restrict__ out, const float* __restrict__ bias) {
  __shared__ __align__(16) u16 lA[128 * 32];
  __shared__ __align__(16) u16 lB[128 * 32];
  const int tid = threadIdx.x;
  const int wid = tid >> 6, lane = tid & 63;
  const int m0 = blockIdx.x * 128, n0 = blockIdx.y * 128;
  const int wm = (wid >> 1) * 64, wn = (wid & 1) * 64;
  const int g = lane >> 4, r16 = lane & 15;

  f32x4 acc[4][4] = {};

  const int srow = wid * 16 + (lane >> 2);
  const int scol = (lane & 3) * 8;
  const u16* gA = A + (size_t)(m0 + srow) * Kdim + scol;
  const u16* gB = Bw + (size_t)(n0 + srow) * Kdim + scol;
  u16* lAw = lA + wid * 512;
  u16* lBw = lB + wid * 512;

  for (int k0 = 0; k0 < Kdim; k0 += 32) {
    gload16(gA + k0, lAw);
    gload16(gA + (size_t)64 * Kdim + k0, lAw + 2048);
    gload16(gB + k0, lBw);
    gload16(gB + (size_t)64 * Kdim + k0, lBw + 2048);
    __syncthreads();
    bf16x8 af[4], bfr[4];
#pragma unroll
    for (int i = 0; i < 4; ++i) af[i] = *(const bf16x8*)(lA + (wm + i * 16 + r16) * 32 + g * 8);
#pragma unroll
    for (int j = 0; j < 4; ++j) bfr[j] = *(const bf16x8*)(lB + (wn + j * 16 + r16) * 32 + g * 8);
#pragma unroll
    for (int i = 0; i < 4; ++i)
#pragma unroll
      for (int j = 0; j < 4; ++j)
        acc[i][j] = __builtin_amdgcn_mfma_f32_16x16x32_bf16(af[i], bfr[j], acc[i][j], 0, 0, 0);
    __syncthreads();
  }

#pragma unroll
  for (int i = 0; i < 4; ++i) {
    const int gm = m0 + wm + i * 16 + g * 4;  // multiple of 4
#pragma unroll
    for (int j = 0; j < 4; ++j) {
      const int gn = n0 + wn + j * 16 + r16;
      if constexpr (MODE == 1) {
        const float bv = bias[gn];
#pragma unroll
        for (int r = 0; r < 4; ++r) out[(size_t)(gm + r) * Ndim + gn] = acc[i][j][r] + bv;
      } else {
        const int t = gn / 768;
        const int rem = gn - t * 768;
        const int h = rem >> 6, d = rem & 63;
        if (t == 2) {
          // vT[b*12+h][d][n], 4 consecutive n -> one 8B store
          u16x4 pk;
#pragma unroll
          for (int r = 0; r < 4; ++r) pk[r] = f2bf(acc[i][j][r]);
          const int b = gm >> 10, n = gm & 1023;
          *(u16x4*)(vTb + ((size_t)((b * 12 + h) * 64 + d)) * 1024 + n) = pk;
        } else {
          u16* dst = (t == 0) ? qb : kb;
          const float sc = (t == 0) ? QSCALE : 1.0f;
#pragma unroll
          for (int r = 0; r < 4; ++r) {
            const int b = (gm + r) >> 10, n = (gm + r) & 1023;
            dst[((size_t)((b * 12 + h) * 1024 + n)) * 64 + d] = f2bf(acc[i][j][r] * sc);
          }
        }
      }
    }
  }
}

// ---------------- per-(b,h) mean of v over tokens ----------------
__global__ __launch_bounds__(256) void vmean_kernel(const u16* __restrict__ vTb,
                                                    float* __restrict__ vmean) {
  const int bh = blockIdx.x, t = threadIdx.x;
  const int d = t >> 2, part = t & 3;
  const u16* src = vTb + ((size_t)bh * 64 + d) * 1024 + part * 256;
  float s = 0.f;
  for (int j = 0; j < 256; j += 8) {
    u16x8 u = *(const u16x8*)(src + j);
#pragma unroll
    for (int e = 0; e < 8; ++e) s += bf2f(u[e]);
  }
  s += __shfl_xor(s, 1);
  s += __shfl_xor(s, 2);
  if (part == 0) vmean[bh * 64 + d] = s * (1.0f / 1024.0f);
}

// ---------------- main body-branch attention (also computes interact rows 0..8) ----------
// Swapped QK^T: S' = mfma(K_frag, Q_frag) -> S'[key 4g+r][query r16].
// Each lane packs 4 consecutive keys of one query -> one 8B store into row-major
// P[query][key] (stride 144B); PV A-fragment is a plain ds_read_b128.
// grid 1536 (XCD-chunk swizzled), 4 waves x 16 rows, 64-key iterations.
// Chunk-0 mask is row-aware: rows 1..8 drop key 0 (their body output is vmean anyway,
// and their computed softmax over keys>=9 IS the interact rows-1..8 result; row 0's
// key-set {0} u [9,1024) is identical for body and interact).
__global__ __launch_bounds__(256) void body_attn(const u16* __restrict__ qg, const u16* __restrict__ kg,
                                                 const u16* __restrict__ vg, const float* __restrict__ vmean,
                                                 u16* __restrict__ og) {
  __shared__ __align__(16) u16 lK[64 * 64];    // [key][hd], 16B chunks XOR-swizzled by key&7
  __shared__ __align__(16) u16 lV[64 * 64];    // [d][tok64], 16B chunks XOR-swizzled by d&7
  __shared__ __align__(16) u16 lP[4][16 * 72]; // per-wave P[query][key], 144B row stride
  __shared__ float lsRed[4][16];

  const int blk = blockIdx.x;
  const int gid = (blk & 7) * 192 + (blk >> 3);  // XCD-chunked (1536 % 8 == 0: bijective)
  const int rt = gid & 15, bh = gid >> 4;
  const int tid = threadIdx.x, wid = tid >> 6, lane = tid & 63;
  const int g = lane >> 4, r16 = lane & 15;
  const int row0 = rt * 64 + wid * 16;

  const u16* qrow = qg + ((size_t)bh * 1024 + row0 + r16) * 64;
  const bf16x8 aq0 = *(const bf16x8*)(qrow + g * 8);
  const bf16x8 aq1 = *(const bf16x8*)(qrow + 32 + g * 8);

  // staging: K rows are 64 elems (128B = 8 chunks); V rows are 64 tokens (128B = 8 chunks).
  // Each wave stages 2 sub-blocks of 8 rows. Source chunk pre-swizzled: (lch ^ row&7).
  const int lrow = lane >> 3, lch = lane & 7;
  const int swz = (lch ^ lrow) * 8;
  const int j0 = wid * 2;
  const u16* gK = kg + (size_t)bh * 65536 + (size_t)(j0 * 8 + lrow) * 64 + swz;
  const u16* gV = vg + (size_t)bh * 65536 + (size_t)(j0 * 8 + lrow) * 1024 + swz;
  u16* lKd0 = lK + j0 * 512;
  u16* lKd1 = lK + (j0 + 1) * 512;
  u16* lVd0 = lV + j0 * 512;
  u16* lVd1 = lV + (j0 + 1) * 512;

  f32x4 oa[4] = {};
  float lsum = 0.f;
  u16* lPw = lP[wid];

  for (int c0 = 0; c0 < 1024; c0 += 64) {
    gload16(gK + (size_t)c0 * 64, lKd0);          // keys c0+j0*8 .. +7
    gload16(gK + (size_t)c0 * 64 + 512, lKd1);    // keys c0+(j0+1)*8 .. +7
    gload16(gV + c0, lVd0);                       // d rows j0*8..+7, tokens c0..c0+63
    gload16(gV + c0 + 8192, lVd1);                // d rows (j0+1)*8..+7
    __syncthreads();

#pragma unroll
    for (int kt = 0; kt < 4; ++kt) {
      const int key = kt * 16 + r16;
      const bf16x8 bk0 = *(const bf16x8*)(lK + key * 64 + ((g ^ (key & 7)) * 8));
      const bf16x8 bk1 = *(const bf16x8*)(lK + key * 64 + (((4 + g) ^ (key & 7)) * 8));
      f32x4 S = {};
      S = __builtin_amdgcn_mfma_f32_16x16x32_bf16(bk0, aq0, S, 0, 0, 0);  // S'[key][query]
      S = __builtin_amdgcn_mfma_f32_16x16x32_bf16(bk1, aq1, S, 0, 0, 0);
      float p[4];
#pragma unroll
      for (int r = 0; r < 4; ++r) p[r] = exp2f(S[r]);
      if (c0 == 0 && kt == 0) {
        const int q = row0 + r16;                   // global query row of this lane's column
        const bool dropk0 = (q >= 1 && q <= 8);     // interact rows 1..8: keys >= 9 only
#pragma unroll
        for (int r = 0; r < 4; ++r) {
          const int k = 4 * g + r;
          const bool keep = (k >= 9) || (k == 0 && !dropk0);
          p[r] = keep ? p[r] : 0.f;
        }
      }
      lsum += p[0] + p[1] + p[2] + p[3];
      u16x4 pk;
#pragma unroll
      for (int r = 0; r < 4; ++r) pk[r] = f2bf(p[r]);
      *(u16x4*)((char*)lPw + r16 * 144 + kt * 32 + g * 8) = pk;
    }
#pragma unroll
    for (int m = 0; m < 2; ++m) {
      const bf16x8 ap = *(const bf16x8*)((char*)lPw + r16 * 144 + m * 64 + g * 16);
#pragma unroll
      for (int jt = 0; jt < 4; ++jt) {
        const int d = jt * 16 + r16;
        const bf16x8 bv = *(const bf16x8*)(lV + d * 64 + (((m * 4 + g) ^ (d & 7)) * 8));
        oa[jt] = __builtin_amdgcn_mfma_f32_16x16x32_bf16(ap, bv, oa[jt], 0, 0, 0);
      }
    }
    __syncthreads();
  }

  // lsum is per query r16 (partial over this lane's keys): reduce across g-groups
  lsum += __shfl_xor(lsum, 16);
  lsum += __shfl_xor(lsum, 32);
  if (lane < 16) lsRed[wid][lane] = lsum;  // same-wave write->read: in-order

  const int b = bh / 12, h = bh - b * 12;
#pragma unroll
  for (int r = 0; r < 4; ++r) {
    const int grow = row0 + 4 * g + r;
    const bool full = (grow >= 1 && grow <= 8);
    const float inv = 1.f / lsRed[wid][4 * g + r];
#pragma unroll
    for (int jt = 0; jt < 4; ++jt) {
      const int d = jt * 16 + r16;
      const float vi = oa[jt][r] * inv;
      const float vb = full ? vmean[bh * 64 + d] : vi;
      og[((size_t)(8192 + b * 1024 + grow)) * 768 + h * 64 + d] = f2bf(vb);
      if (grow <= 8)  // interact rows 0..8 (only the rt==0 block reaches here)
        og[((size_t)(16384 + b * 1024 + grow)) * 768 + h * 64 + d] = f2bf(vi);
    }
  }
}

// ---------------- small branches (E path only) ----------------
// queries = 64 rows/block over all 1024 rows, keys [0,16) masked k<9.
//   grow < 9 : head rows 0..8 (computed)
//   grow >= 9: interact rows>=9 (computed) + head rows>=9 (vmean fill)
__global__ __launch_bounds__(256) void smalls_attn(const u16* __restrict__ qg, const u16* __restrict__ kg,
                                                   const u16* __restrict__ vg, const float* __restrict__ vmean,
                                                   u16* __restrict__ og) {
  __shared__ __align__(16) u16 lP2[4][16 * 40];  // per-wave P[query][key 0..31], 80B stride
  __shared__ float lsRed[4][16];
  const int bh = blockIdx.y;
  const int b = bh / 12, h = bh - b * 12;
  const int tid = threadIdx.x, wid = tid >> 6, lane = tid & 63;
  const int g = lane >> 4, r16 = lane & 15;
  u16* lPw = lP2[wid];

  const int row0 = blockIdx.x * 64 + wid * 16;
  const u16* qrow = qg + ((size_t)bh * 1024 + row0 + r16) * 64;
  const bf16x8 aq0 = *(const bf16x8*)(qrow + g * 8);
  const bf16x8 aq1 = *(const bf16x8*)(qrow + 32 + g * 8);
  const u16* krow = kg + ((size_t)bh * 1024 + r16) * 64;  // keys 0..15
  const bf16x8 bk0 = *(const bf16x8*)(krow + g * 8);
  const bf16x8 bk1 = *(const bf16x8*)(krow + 32 + g * 8);
  f32x4 S = {};
  S = __builtin_amdgcn_mfma_f32_16x16x32_bf16(bk0, aq0, S, 0, 0, 0);  // S'[key][query]
  S = __builtin_amdgcn_mfma_f32_16x16x32_bf16(bk1, aq1, S, 0, 0, 0);
  float p[4];
  float lsum = 0.f;
#pragma unroll
  for (int r = 0; r < 4; ++r) {
    const int k = 4 * g + r;
    p[r] = (k < 9) ? exp2f(S[r]) : 0.f;
    lsum += p[r];
  }
  {
    u16x4 pk;
#pragma unroll
    for (int r = 0; r < 4; ++r) pk[r] = f2bf(p[r]);
    *(u16x4*)((char*)lPw + r16 * 80 + g * 8) = pk;
    u16x4 z = {0, 0, 0, 0};
    *(u16x4*)((char*)lPw + r16 * 80 + 32 + g * 8) = z;  // keys 16..31 = 0
  }
  lsum += __shfl_xor(lsum, 16);
  lsum += __shfl_xor(lsum, 32);
  if (lane < 16) lsRed[wid][lane] = lsum;
  const bf16x8 ap = *(const bf16x8*)((char*)lPw + r16 * 80 + g * 16);
  f32x4 oa[4] = {};
#pragma unroll
  for (int jt = 0; jt < 4; ++jt) {
    const u16* vrow = vg + ((size_t)bh * 64 + jt * 16 + r16) * 1024;  // tokens 0..31
    const bf16x8 bv = *(const bf16x8*)(vrow + g * 8);
    oa[jt] = __builtin_amdgcn_mfma_f32_16x16x32_bf16(ap, bv, oa[jt], 0, 0, 0);
  }
#pragma unroll
  for (int r = 0; r < 4; ++r) {
    const int grow = row0 + 4 * g + r;
    const float inv = 1.f / lsRed[wid][4 * g + r];
#pragma unroll
    for (int jt = 0; jt < 4; ++jt) {
      const int d = jt * 16 + r16;
      const float v = oa[jt][r] * inv;
      if (grow >= 9) {
        og[((size_t)(16384 + b * 1024 + grow)) * 768 + h * 64 + d] = f2bf(v);          // interact
        og[((size_t)(b * 1024 + grow)) * 768 + h * 64 + d] = f2bf(vmean[bh * 64 + d]); // head fill
      } else {
        og[((size_t)(b * 1024 + grow)) * 768 + h * 64 + d] = f2bf(v);                  // head 0..8
      }
    }
  }
}

// ---------------- host launcher ----------------
extern "C" void kernel_launch(void* const* d_in, const int* in_sizes, int n_in,
                              void* d_out, int out_size, void* d_ws, size_t ws_size,
                              hipStream_t stream) {
  (void)in_sizes; (void)n_in; (void)out_size; (void)ws_size;
  const float* x      = (const float*)d_in[0];
  const float* w_qkv  = (const float*)d_in[1];
  const float* w_proj = (const float*)d_in[2];
  const float* b_proj = (const float*)d_in[3];

  char* ws = (char*)d_ws;
  u16* xb     = (u16*)(ws + 0);
  u16* wqkvb  = (u16*)(ws + 12582912);
  u16* wprojb = (u16*)(ws + 16121856);
  u16* qb     = (u16*)(ws + 17301504);
  u16* kb     = (u16*)(ws + 29884416);
  u16* vTb    = (u16*)(ws + 42467328);
  float* vmn  = (float*)(ws + 55050240);
  u16* ob     = (u16*)(ws + 55074816);

  cvt_kernel<<<6144, 256, 0, stream>>>(x, xb, 1572864);
  cvt_kernel<<<1728, 256, 0, stream>>>(w_qkv, wqkvb, 442368);
  cvt_kernel<<<576, 256, 0, stream>>>(w_proj, wprojb, 147456);

  gemm_bt<0, 8192, 2304, 768><<<dim3(64, 18), 256, 0, stream>>>(
      xb, wqkvb, qb, kb, vTb, nullptr, nullptr);

  vmean_kernel<<<96, 256, 0, stream>>>(vTb, vmn);

  body_attn<<<1536, 256, 0, stream>>>(qb, kb, vTb, vmn, ob);
  smalls_attn<<<dim3(16, 96), 256, 0, stream>>>(qb, kb, vTb, vmn, ob);

  gemm_bt<1, 24576, 768, 768><<<dim3(192, 6), 256, 0, stream>>>(
      ob, wprojb, nullptr, nullptr, nullptr, (float*)d_out, b_proj);
}

// Round 6
// 186.953 us; speedup vs baseline: 1.2066x; 1.0399x over previous
//
#include <hip/hip_runtime.h>
#include <stdint.h>

typedef unsigned short u16;
typedef unsigned int u32;
using f32x4 = __attribute__((ext_vector_type(4))) float;
using bf16x8 = __attribute__((ext_vector_type(8))) short;
using u16x8 = __attribute__((ext_vector_type(8))) unsigned short;
using u16x4 = __attribute__((ext_vector_type(4))) unsigned short;

#define QSCALE 0.18033688f  // 0.125 * log2(e): scores in exp2 domain

__device__ __forceinline__ u16 f2bf(float f) {
  u32 u = __float_as_uint(f);
  u32 r = (u + 0x7FFFu + ((u >> 16) & 1u)) >> 16;  // RNE
  return (u16)r;
}
__device__ __forceinline__ float bf2f(u16 h) { return __uint_as_float(((u32)h) << 16); }

__device__ __forceinline__ void gload16(const void* g, void* l) {
  __builtin_amdgcn_global_load_lds((const __attribute__((address_space(1))) void*)g,
                                   (__attribute__((address_space(3))) void*)l, 16, 0, 0);
}

// ---------------- fp32 -> bf16 convert, 3 tensors in one launch ----------------
__global__ __launch_bounds__(256) void cvt3_kernel(const float* __restrict__ a, u16* __restrict__ da, int n4a,
                                                   const float* __restrict__ b, u16* __restrict__ db, int n4b,
                                                   const float* __restrict__ c, u16* __restrict__ dc, int n4c) {
  int i = blockIdx.x * 256 + threadIdx.x;
  const float* src;
  u16* dst;
  int n;
  if (i < n4a) {
    src = a; dst = da; n = i;
  } else if (i < n4a + n4b) {
    src = b; dst = db; n = i - n4a;
  } else if (i < n4a + n4b + n4c) {
    src = c; dst = dc; n = i - n4a - n4b;
  } else {
    return;
  }
  const float4 f = ((const float4*)src)[n];
  u16x4 o;
  o[0] = f2bf(f.x); o[1] = f2bf(f.y); o[2] = f2bf(f.z); o[3] = f2bf(f.w);
  ((u16x4*)dst)[n] = o;
}

// ---------------- 128x128 bf16 GEMM, C = A * B^T, 2-phase double-buffered ----------------
// MODE 0: epilogue scatters qkv into q[B,H,N,64] (pre-scaled by QSCALE), k[B,H,N,64], vT[B,H,64,N]
// MODE 1: epilogue writes fp32 out[M][N] += bias[n]
template <int MODE, int Mdim, int Ndim, int Kdim>
__global__ __launch_bounds__(256) void gemm_bt(const u16* __restrict__ A, const u16* __restrict__ Bw,
                                               u16* __restrict__ qb, u16* __restrict__ kb,
                                               u16* __restrict__ vTb,
                                               float* __restrict__ out, const float* __restrict__ bias) {
  __shared__ __align__(16) u16 lA[2][128 * 32];
  __shared__ __align__(16) u16 lB[2][128 * 32];
  const int tid = threadIdx.x;
  const int wid = tid >> 6, lane = tid & 63;
  const int m0 = blockIdx.x * 128, n0 = blockIdx.y * 128;
  const int wm = (wid >> 1) * 64, wn = (wid & 1) * 64;
  const int g = lane >> 4, r16 = lane & 15;

  f32x4 acc[4][4] = {};

  const int srow = wid * 16 + (lane >> 2);
  const int scol = (lane & 3) * 8;
  const u16* gA = A + (size_t)(m0 + srow) * Kdim + scol;
  const u16* gB = Bw + (size_t)(n0 + srow) * Kdim + scol;

  // prologue: stage k0=0 into buffer 0
  gload16(gA, lA[0] + wid * 512);
  gload16(gA + (size_t)64 * Kdim, lA[0] + wid * 512 + 2048);
  gload16(gB, lB[0] + wid * 512);
  gload16(gB + (size_t)64 * Kdim, lB[0] + wid * 512 + 2048);
  __syncthreads();  // implicit vmcnt(0) drain

  int cur = 0;
  for (int k0 = 0; k0 < Kdim; k0 += 32) {
    if (k0 + 32 < Kdim) {  // prefetch next K-tile into the other buffer
      const int nk = k0 + 32;
      u16* lAn = lA[cur ^ 1] + wid * 512;
      u16* lBn = lB[cur ^ 1] + wid * 512;
      gload16(gA + nk, lAn);
      gload16(gA + (size_t)64 * Kdim + nk, lAn + 2048);
      gload16(gB + nk, lBn);
      gload16(gB + (size_t)64 * Kdim + nk, lBn + 2048);
    }
    const u16* lAc = lA[cur];
    const u16* lBc = lB[cur];
    bf16x8 af[4], bfr[4];
#pragma unroll
    for (int i = 0; i < 4; ++i) af[i] = *(const bf16x8*)(lAc + (wm + i * 16 + r16) * 32 + g * 8);
#pragma unroll
    for (int j = 0; j < 4; ++j) bfr[j] = *(const bf16x8*)(lBc + (wn + j * 16 + r16) * 32 + g * 8);
#pragma unroll
    for (int i = 0; i < 4; ++i)
#pragma unroll
      for (int j = 0; j < 4; ++j)
        acc[i][j] = __builtin_amdgcn_mfma_f32_16x16x32_bf16(af[i], bfr[j], acc[i][j], 0, 0, 0);
    __syncthreads();  // drains this iter's prefetch + all waves' ds_reads of cur
    cur ^= 1;
  }

#pragma unroll
  for (int i = 0; i < 4; ++i) {
    const int gm = m0 + wm + i * 16 + g * 4;  // multiple of 4
#pragma unroll
    for (int j = 0; j < 4; ++j) {
      const int gn = n0 + wn + j * 16 + r16;
      if constexpr (MODE == 1) {
        const float bv = bias[gn];
#pragma unroll
        for (int r = 0; r < 4; ++r) out[(size_t)(gm + r) * Ndim + gn] = acc[i][j][r] + bv;
      } else {
        const int t = gn / 768;
        const int rem = gn - t * 768;
        const int h = rem >> 6, d = rem & 63;
        if (t == 2) {
          // vT[b*12+h][d][n], 4 consecutive n -> one 8B store
          u16x4 pk;
#pragma unroll
          for (int r = 0; r < 4; ++r) pk[r] = f2bf(acc[i][j][r]);
          const int b = gm >> 10, n = gm & 1023;
          *(u16x4*)(vTb + ((size_t)((b * 12 + h) * 64 + d)) * 1024 + n) = pk;
        } else {
          u16* dst = (t == 0) ? qb : kb;
          const float sc = (t == 0) ? QSCALE : 1.0f;
#pragma unroll
          for (int r = 0; r < 4; ++r) {
            const int b = (gm + r) >> 10, n = (gm + r) & 1023;
            dst[((size_t)((b * 12 + h) * 1024 + n)) * 64 + d] = f2bf(acc[i][j][r] * sc);
          }
        }
      }
    }
  }
}

// ---------------- per-(b,h) mean of v over tokens ----------------
__global__ __launch_bounds__(256) void vmean_kernel(const u16* __restrict__ vTb,
                                                    float* __restrict__ vmean) {
  const int bh = blockIdx.x, t = threadIdx.x;
  const int d = t >> 2, part = t & 3;
  const u16* src = vTb + ((size_t)bh * 64 + d) * 1024 + part * 256;
  float s = 0.f;
  for (int j = 0; j < 256; j += 8) {
    u16x8 u = *(const u16x8*)(src + j);
#pragma unroll
    for (int e = 0; e < 8; ++e) s += bf2f(u[e]);
  }
  s += __shfl_xor(s, 1);
  s += __shfl_xor(s, 2);
  if (part == 0) vmean[bh * 64 + d] = s * (1.0f / 1024.0f);
}

// ---------------- main body-branch attention (also computes interact rows 0..8) ----------
// Swapped QK^T: S' = mfma(K_frag, Q_frag) -> S'[key 4g+r][query r16].
// Each lane packs 4 consecutive keys of one query -> one 8B store into row-major
// P[query][key] (stride 144B); PV A-fragment is a plain ds_read_b128.
// 2-phase double-buffered K/V staging; grid 1536 (XCD-chunk swizzled), 4 waves x 16 rows.
// Chunk-0 mask is row-aware: rows 1..8 drop key 0 (their body output is vmean anyway,
// and their computed softmax over keys>=9 IS the interact rows-1..8 result; row 0's
// key-set {0} u [9,1024) is identical for body and interact).
__global__ __launch_bounds__(256) void body_attn(const u16* __restrict__ qg, const u16* __restrict__ kg,
                                                 const u16* __restrict__ vg, const float* __restrict__ vmean,
                                                 u16* __restrict__ og) {
  __shared__ __align__(16) u16 lK[2][64 * 64];  // [key][hd], 16B chunks XOR-swizzled by key&7
  __shared__ __align__(16) u16 lV[2][64 * 64];  // [d][tok64], 16B chunks XOR-swizzled by d&7
  __shared__ __align__(16) u16 lP[4][16 * 72];  // per-wave P[query][key], 144B row stride
  __shared__ float lsRed[4][16];

  const int blk = blockIdx.x;
  const int gid = (blk & 7) * 192 + (blk >> 3);  // XCD-chunked (1536 % 8 == 0: bijective)
  const int rt = gid & 15, bh = gid >> 4;
  const int tid = threadIdx.x, wid = tid >> 6, lane = tid & 63;
  const int g = lane >> 4, r16 = lane & 15;
  const int row0 = rt * 64 + wid * 16;

  const u16* qrow = qg + ((size_t)bh * 1024 + row0 + r16) * 64;
  const bf16x8 aq0 = *(const bf16x8*)(qrow + g * 8);
  const bf16x8 aq1 = *(const bf16x8*)(qrow + 32 + g * 8);

  // staging: K rows are 64 elems (128B = 8 chunks); V rows are 64 tokens (128B = 8 chunks).
  // Each wave stages 2 sub-blocks of 8 rows. Source chunk pre-swizzled: (lch ^ row&7).
  const int lrow = lane >> 3, lch = lane & 7;
  const int swz = (lch ^ lrow) * 8;
  const int j0 = wid * 2;
  const u16* gK = kg + (size_t)bh * 65536 + (size_t)(j0 * 8 + lrow) * 64 + swz;
  const u16* gV = vg + (size_t)bh * 65536 + (size_t)(j0 * 8 + lrow) * 1024 + swz;

  f32x4 oa[4] = {};
  float lsum = 0.f;
  u16* lPw = lP[wid];

  // prologue: stage chunk 0 into buffer 0
  gload16(gK, lK[0] + j0 * 512);
  gload16(gK + 512, lK[0] + (j0 + 1) * 512);
  gload16(gV, lV[0] + j0 * 512);
  gload16(gV + 8192, lV[0] + (j0 + 1) * 512);
  __syncthreads();

  int cur = 0;
  for (int c0 = 0; c0 < 1024; c0 += 64) {
    if (c0 + 64 < 1024) {  // prefetch next 64-key chunk
      const int nc = c0 + 64;
      gload16(gK + (size_t)nc * 64, lK[cur ^ 1] + j0 * 512);
      gload16(gK + (size_t)nc * 64 + 512, lK[cur ^ 1] + (j0 + 1) * 512);
      gload16(gV + nc, lV[cur ^ 1] + j0 * 512);
      gload16(gV + nc + 8192, lV[cur ^ 1] + (j0 + 1) * 512);
    }
    const u16* lKc = lK[cur];
    const u16* lVc = lV[cur];

#pragma unroll
    for (int kt = 0; kt < 4; ++kt) {
      const int key = kt * 16 + r16;
      const bf16x8 bk0 = *(const bf16x8*)(lKc + key * 64 + ((g ^ (key & 7)) * 8));
      const bf16x8 bk1 = *(const bf16x8*)(lKc + key * 64 + (((4 + g) ^ (key & 7)) * 8));
      f32x4 S = {};
      S = __builtin_amdgcn_mfma_f32_16x16x32_bf16(bk0, aq0, S, 0, 0, 0);  // S'[key][query]
      S = __builtin_amdgcn_mfma_f32_16x16x32_bf16(bk1, aq1, S, 0, 0, 0);
      float p[4];
#pragma unroll
      for (int r = 0; r < 4; ++r) p[r] = exp2f(S[r]);
      if (c0 == 0 && kt == 0) {
        const int q = row0 + r16;                   // global query row of this lane's column
        const bool dropk0 = (q >= 1 && q <= 8);     // interact rows 1..8: keys >= 9 only
#pragma unroll
        for (int r = 0; r < 4; ++r) {
          const int k = 4 * g + r;
          const bool keep = (k >= 9) || (k == 0 && !dropk0);
          p[r] = keep ? p[r] : 0.f;
        }
      }
      lsum += p[0] + p[1] + p[2] + p[3];
      u16x4 pk;
#pragma unroll
      for (int r = 0; r < 4; ++r) pk[r] = f2bf(p[r]);
      *(u16x4*)((char*)lPw + r16 * 144 + kt * 32 + g * 8) = pk;
    }
#pragma unroll
    for (int m = 0; m < 2; ++m) {
      const bf16x8 ap = *(const bf16x8*)((char*)lPw + r16 * 144 + m * 64 + g * 16);
#pragma unroll
      for (int jt = 0; jt < 4; ++jt) {
        const int d = jt * 16 + r16;
        const bf16x8 bv = *(const bf16x8*)(lVc + d * 64 + (((m * 4 + g) ^ (d & 7)) * 8));
        oa[jt] = __builtin_amdgcn_mfma_f32_16x16x32_bf16(ap, bv, oa[jt], 0, 0, 0);
      }
    }
    __syncthreads();  // drains prefetch + all waves' reads of cur
    cur ^= 1;
  }

  // lsum is per query r16 (partial over this lane's keys): reduce across g-groups
  lsum += __shfl_xor(lsum, 16);
  lsum += __shfl_xor(lsum, 32);
  if (lane < 16) lsRed[wid][lane] = lsum;  // same-wave write->read: in-order

  const int b = bh / 12, h = bh - b * 12;
#pragma unroll
  for (int r = 0; r < 4; ++r) {
    const int grow = row0 + 4 * g + r;
    const bool full = (grow >= 1 && grow <= 8);
    const float inv = 1.f / lsRed[wid][4 * g + r];
#pragma unroll
    for (int jt = 0; jt < 4; ++jt) {
      const int d = jt * 16 + r16;
      const float vi = oa[jt][r] * inv;
      const float vb = full ? vmean[bh * 64 + d] : vi;
      og[((size_t)(8192 + b * 1024 + grow)) * 768 + h * 64 + d] = f2bf(vb);
      if (grow <= 8)  // interact rows 0..8 (only the rt==0 block reaches here)
        og[((size_t)(16384 + b * 1024 + grow)) * 768 + h * 64 + d] = f2bf(vi);
    }
  }
}

// ---------------- small branches (E path only) ----------------
// queries = 64 rows/block over all 1024 rows, keys [0,16) masked k<9.
//   grow < 9 : head rows 0..8 (computed)
//   grow >= 9: interact rows>=9 (computed) + head rows>=9 (vmean fill)
__global__ __launch_bounds__(256) void smalls_attn(const u16* __restrict__ qg, const u16* __restrict__ kg,
                                                   const u16* __restrict__ vg, const float* __restrict__ vmean,
                                                   u16* __restrict__ og) {
  __shared__ __align__(16) u16 lP2[4][16 * 40];  // per-wave P[query][key 0..31], 80B stride
  __shared__ float lsRed[4][16];
  const int bh = blockIdx.y;
  const int b = bh / 12, h = bh - b * 12;
  const int tid = threadIdx.x, wid = tid >> 6, lane = tid & 63;
  const int g = lane >> 4, r16 = lane & 15;
  u16* lPw = lP2[wid];

  const int row0 = blockIdx.x * 64 + wid * 16;
  const u16* qrow = qg + ((size_t)bh * 1024 + row0 + r16) * 64;
  const bf16x8 aq0 = *(const bf16x8*)(qrow + g * 8);
  const bf16x8 aq1 = *(const bf16x8*)(qrow + 32 + g * 8);
  const u16* krow = kg + ((size_t)bh * 1024 + r16) * 64;  // keys 0..15
  const bf16x8 bk0 = *(const bf16x8*)(krow + g * 8);
  const bf16x8 bk1 = *(const bf16x8*)(krow + 32 + g * 8);
  f32x4 S = {};
  S = __builtin_amdgcn_mfma_f32_16x16x32_bf16(bk0, aq0, S, 0, 0, 0);  // S'[key][query]
  S = __builtin_amdgcn_mfma_f32_16x16x32_bf16(bk1, aq1, S, 0, 0, 0);
  float p[4];
  float lsum = 0.f;
#pragma unroll
  for (int r = 0; r < 4; ++r) {
    const int k = 4 * g + r;
    p[r] = (k < 9) ? exp2f(S[r]) : 0.f;
    lsum += p[r];
  }
  {
    u16x4 pk;
#pragma unroll
    for (int r = 0; r < 4; ++r) pk[r] = f2bf(p[r]);
    *(u16x4*)((char*)lPw + r16 * 80 + g * 8) = pk;
    u16x4 z = {0, 0, 0, 0};
    *(u16x4*)((char*)lPw + r16 * 80 + 32 + g * 8) = z;  // keys 16..31 = 0
  }
  lsum += __shfl_xor(lsum, 16);
  lsum += __shfl_xor(lsum, 32);
  if (lane < 16) lsRed[wid][lane] = lsum;
  const bf16x8 ap = *(const bf16x8*)((char*)lPw + r16 * 80 + g * 16);
  f32x4 oa[4] = {};
#pragma unroll
  for (int jt = 0; jt < 4; ++jt) {
    const u16* vrow = vg + ((size_t)bh * 64 + jt * 16 + r16) * 1024;  // tokens 0..31
    const bf16x8 bv = *(const bf16x8*)(vrow + g * 8);
    oa[jt] = __builtin_amdgcn_mfma_f32_16x16x32_bf16(ap, bv, oa[jt], 0, 0, 0);
  }
#pragma unroll
  for (int r = 0; r < 4; ++r) {
    const int grow = row0 + 4 * g + r;
    const float inv = 1.f / lsRed[wid][4 * g + r];
#pragma unroll
    for (int jt = 0; jt < 4; ++jt) {
      const int d = jt * 16 + r16;
      const float v = oa[jt][r] * inv;
      if (grow >= 9) {
        og[((size_t)(16384 + b * 1024 + grow)) * 768 + h * 64 + d] = f2bf(v);          // interact
        og[((size_t)(b * 1024 + grow)) * 768 + h * 64 + d] = f2bf(vmean[bh * 64 + d]); // head fill
      } else {
        og[((size_t)(b * 1024 + grow)) * 768 + h * 64 + d] = f2bf(v);                  // head 0..8
      }
    }
  }
}

// ---------------- host launcher ----------------
extern "C" void kernel_launch(void* const* d_in, const int* in_sizes, int n_in,
                              void* d_out, int out_size, void* d_ws, size_t ws_size,
                              hipStream_t stream) {
  (void)in_sizes; (void)n_in; (void)out_size; (void)ws_size;
  const float* x      = (const float*)d_in[0];
  const float* w_qkv  = (const float*)d_in[1];
  const float* w_proj = (const float*)d_in[2];
  const float* b_proj = (const float*)d_in[3];

  char* ws = (char*)d_ws;
  u16* xb     = (u16*)(ws + 0);
  u16* wqkvb  = (u16*)(ws + 12582912);
  u16* wprojb = (u16*)(ws + 16121856);
  u16* qb     = (u16*)(ws + 17301504);
  u16* kb     = (u16*)(ws + 29884416);
  u16* vTb    = (u16*)(ws + 42467328);
  float* vmn  = (float*)(ws + 55050240);
  u16* ob     = (u16*)(ws + 55074816);

  cvt3_kernel<<<8449, 256, 0, stream>>>(x, xb, 1572864, w_qkv, wqkvb, 442368, w_proj, wprojb, 147456);

  gemm_bt<0, 8192, 2304, 768><<<dim3(64, 18), 256, 0, stream>>>(
      xb, wqkvb, qb, kb, vTb, nullptr, nullptr);

  vmean_kernel<<<96, 256, 0, stream>>>(vTb, vmn);

  body_attn<<<1536, 256, 0, stream>>>(qb, kb, vTb, vmn, ob);
  smalls_attn<<<dim3(16, 96), 256, 0, stream>>>(qb, kb, vTb, vmn, ob);

  gemm_bt<1, 24576, 768, 768><<<dim3(192, 6), 256, 0, stream>>>(
      ob, wprojb, nullptr, nullptr, nullptr, (float*)d_out, b_proj);
}

// Round 7
// 181.608 us; speedup vs baseline: 1.2421x; 1.0294x over previous
//
#include <hip/hip_runtime.h>
#include <stdint.h>

typedef unsigned short u16;
typedef unsigned int u32;
using f32x4 = __attribute__((ext_vector_type(4))) float;
using bf16x8 = __attribute__((ext_vector_type(8))) short;
using u16x8 = __attribute__((ext_vector_type(8))) unsigned short;
using u16x4 = __attribute__((ext_vector_type(4))) unsigned short;
using u32x2 = __attribute__((ext_vector_type(2))) unsigned int;

#define QSCALE 0.18033688f  // 0.125 * log2(e): scores in exp2 domain

__device__ __forceinline__ u16 f2bf(float f) {
  u32 u = __float_as_uint(f);
  u32 r = (u + 0x7FFFu + ((u >> 16) & 1u)) >> 16;  // RNE
  return (u16)r;
}
__device__ __forceinline__ float bf2f(u16 h) { return __uint_as_float(((u32)h) << 16); }

// truncation-pack two f32 -> packed bf16 pair (hi|lo). Bias cancelled by MFMA-computed
// softmax denominator over the SAME truncated values.
__device__ __forceinline__ u32 pack_trunc(float lo, float hi) {
  return (__float_as_uint(hi) & 0xFFFF0000u) | (__float_as_uint(lo) >> 16);
}

__device__ __forceinline__ void gload16(const void* g, void* l) {
  __builtin_amdgcn_global_load_lds((const __attribute__((address_space(1))) void*)g,
                                   (__attribute__((address_space(3))) void*)l, 16, 0, 0);
}

// ---------------- fp32 -> bf16 convert, 3 tensors in one launch ----------------
__global__ __launch_bounds__(256) void cvt3_kernel(const float* __restrict__ a, u16* __restrict__ da, int n4a,
                                                   const float* __restrict__ b, u16* __restrict__ db, int n4b,
                                                   const float* __restrict__ c, u16* __restrict__ dc, int n4c) {
  int i = blockIdx.x * 256 + threadIdx.x;
  const float* src;
  u16* dst;
  int n;
  if (i < n4a) {
    src = a; dst = da; n = i;
  } else if (i < n4a + n4b) {
    src = b; dst = db; n = i - n4a;
  } else if (i < n4a + n4b + n4c) {
    src = c; dst = dc; n = i - n4a - n4b;
  } else {
    return;
  }
  const float4 f = ((const float4*)src)[n];
  u16x4 o;
  o[0] = f2bf(f.x); o[1] = f2bf(f.y); o[2] = f2bf(f.z); o[3] = f2bf(f.w);
  ((u16x4*)dst)[n] = o;
}

// ---------------- 128x128 bf16 GEMM, C = A * B^T, 2-phase double-buffered ----------------
// MODE 0: epilogue scatters qkv into q[B,H,N,64] (pre-scaled by QSCALE), k[B,H,N,64], vT[B,H,64,N]
// MODE 1: epilogue writes fp32 out[M][N] += bias[n]
template <int MODE, int Mdim, int Ndim, int Kdim>
__global__ __launch_bounds__(256) void gemm_bt(const u16* __restrict__ A, const u16* __restrict__ Bw,
                                               u16* __restrict__ qb, u16* __restrict__ kb,
                                               u16* __restrict__ vTb,
                                               float* __restrict__ out, const float* __restrict__ bias) {
  __shared__ __align__(16) u16 lA[2][128 * 32];
  __shared__ __align__(16) u16 lB[2][128 * 32];
  const int tid = threadIdx.x;
  const int wid = tid >> 6, lane = tid & 63;
  const int m0 = blockIdx.x * 128, n0 = blockIdx.y * 128;
  const int wm = (wid >> 1) * 64, wn = (wid & 1) * 64;
  const int g = lane >> 4, r16 = lane & 15;

  f32x4 acc[4][4] = {};

  const int srow = wid * 16 + (lane >> 2);
  const int scol = (lane & 3) * 8;
  const u16* gA = A + (size_t)(m0 + srow) * Kdim + scol;
  const u16* gB = Bw + (size_t)(n0 + srow) * Kdim + scol;

  // prologue: stage k0=0 into buffer 0
  gload16(gA, lA[0] + wid * 512);
  gload16(gA + (size_t)64 * Kdim, lA[0] + wid * 512 + 2048);
  gload16(gB, lB[0] + wid * 512);
  gload16(gB + (size_t)64 * Kdim, lB[0] + wid * 512 + 2048);
  __syncthreads();  // implicit vmcnt(0) drain

  int cur = 0;
  for (int k0 = 0; k0 < Kdim; k0 += 32) {
    if (k0 + 32 < Kdim) {  // prefetch next K-tile into the other buffer
      const int nk = k0 + 32;
      u16* lAn = lA[cur ^ 1] + wid * 512;
      u16* lBn = lB[cur ^ 1] + wid * 512;
      gload16(gA + nk, lAn);
      gload16(gA + (size_t)64 * Kdim + nk, lAn + 2048);
      gload16(gB + nk, lBn);
      gload16(gB + (size_t)64 * Kdim + nk, lBn + 2048);
    }
    const u16* lAc = lA[cur];
    const u16* lBc = lB[cur];
    bf16x8 af[4], bfr[4];
#pragma unroll
    for (int i = 0; i < 4; ++i) af[i] = *(const bf16x8*)(lAc + (wm + i * 16 + r16) * 32 + g * 8);
#pragma unroll
    for (int j = 0; j < 4; ++j) bfr[j] = *(const bf16x8*)(lBc + (wn + j * 16 + r16) * 32 + g * 8);
#pragma unroll
    for (int i = 0; i < 4; ++i)
#pragma unroll
      for (int j = 0; j < 4; ++j)
        acc[i][j] = __builtin_amdgcn_mfma_f32_16x16x32_bf16(af[i], bfr[j], acc[i][j], 0, 0, 0);
    __syncthreads();  // drains this iter's prefetch + all waves' ds_reads of cur
    cur ^= 1;
  }

#pragma unroll
  for (int i = 0; i < 4; ++i) {
    const int gm = m0 + wm + i * 16 + g * 4;  // multiple of 4
#pragma unroll
    for (int j = 0; j < 4; ++j) {
      const int gn = n0 + wn + j * 16 + r16;
      if constexpr (MODE == 1) {
        const float bv = bias[gn];
#pragma unroll
        for (int r = 0; r < 4; ++r) out[(size_t)(gm + r) * Ndim + gn] = acc[i][j][r] + bv;
      } else {
        const int t = gn / 768;
        const int rem = gn - t * 768;
        const int h = rem >> 6, d = rem & 63;
        if (t == 2) {
          // vT[b*12+h][d][n], 4 consecutive n -> one 8B store
          u16x4 pk;
#pragma unroll
          for (int r = 0; r < 4; ++r) pk[r] = f2bf(acc[i][j][r]);
          const int b = gm >> 10, n = gm & 1023;
          *(u16x4*)(vTb + ((size_t)((b * 12 + h) * 64 + d)) * 1024 + n) = pk;
        } else {
          u16* dst = (t == 0) ? qb : kb;
          const float sc = (t == 0) ? QSCALE : 1.0f;
#pragma unroll
          for (int r = 0; r < 4; ++r) {
            const int b = (gm + r) >> 10, n = (gm + r) & 1023;
            dst[((size_t)((b * 12 + h) * 1024 + n)) * 64 + d] = f2bf(acc[i][j][r] * sc);
          }
        }
      }
    }
  }
}

// ---------------- per-(b,h) mean of v over tokens ----------------
__global__ __launch_bounds__(256) void vmean_kernel(const u16* __restrict__ vTb,
                                                    float* __restrict__ vmean) {
  const int bh = blockIdx.x, t = threadIdx.x;
  const int d = t >> 2, part = t & 3;
  const u16* src = vTb + ((size_t)bh * 64 + d) * 1024 + part * 256;
  float s = 0.f;
  for (int j = 0; j < 256; j += 8) {
    u16x8 u = *(const u16x8*)(src + j);
#pragma unroll
    for (int e = 0; e < 8; ++e) s += bf2f(u[e]);
  }
  s += __shfl_xor(s, 1);
  s += __shfl_xor(s, 2);
  if (part == 0) vmean[bh * 64 + d] = s * (1.0f / 1024.0f);
}

// ---------------- main body-branch attention (also computes interact rows 0..8) ----------
// Swapped QK^T: S' = mfma(K_frag, Q_frag) -> S'[key 4g+r][query r16].
// P truncation-packed (2 bit-ops/pair) into row-major P[query][key] (144B stride);
// PV A-fragment is a plain ds_read_b128. Softmax denominator via ones-row MFMA
// (osum = mfma(P, 1s)) so numerator and denominator use the SAME bf16 P.
// 2-phase double-buffered K/V staging with static buffer indices (manual 2x unroll).
// grid 1536 (XCD-chunk swizzled), 4 waves x 16 rows.
__global__ __launch_bounds__(256) void body_attn(const u16* __restrict__ qg, const u16* __restrict__ kg,
                                                 const u16* __restrict__ vg, const float* __restrict__ vmean,
                                                 u16* __restrict__ og) {
  __shared__ __align__(16) u16 lK[2][64 * 64];  // [key][hd], 16B chunks XOR-swizzled by key&7
  __shared__ __align__(16) u16 lV[2][64 * 64];  // [d][tok64], 16B chunks XOR-swizzled by d&7
  __shared__ __align__(16) u16 lP[4][16 * 72];  // per-wave P[query][key], 144B row stride

  const int blk = blockIdx.x;
  const int gid = (blk & 7) * 192 + (blk >> 3);  // XCD-chunked (1536 % 8 == 0: bijective)
  const int rt = gid & 15, bh = gid >> 4;
  const int tid = threadIdx.x, wid = tid >> 6, lane = tid & 63;
  const int g = lane >> 4, r16 = lane & 15;
  const int row0 = rt * 64 + wid * 16;

  const u16* qrow = qg + ((size_t)bh * 1024 + row0 + r16) * 64;
  const bf16x8 aq0 = *(const bf16x8*)(qrow + g * 8);
  const bf16x8 aq1 = *(const bf16x8*)(qrow + 32 + g * 8);

  // staging: K rows are 64 elems (128B = 8 chunks); V rows are 64 tokens (128B = 8 chunks).
  // Each wave stages 2 sub-blocks of 8 rows. Source chunk pre-swizzled: (lch ^ row&7).
  const int lrow = lane >> 3, lch = lane & 7;
  const int swz = (lch ^ lrow) * 8;
  const int j0 = wid * 2;
  const u16* gK = kg + (size_t)bh * 65536 + (size_t)(j0 * 8 + lrow) * 64 + swz;
  const u16* gV = vg + (size_t)bh * 65536 + (size_t)(j0 * 8 + lrow) * 1024 + swz;

  f32x4 oa[4] = {};
  f32x4 osum = {};
  u16* lPw = lP[wid];

  bf16x8 vones;
#pragma unroll
  for (int i = 0; i < 8; ++i) vones[i] = (short)0x3F80;  // bf16 1.0

  auto stage = [&](int c0, int buf) {
    gload16(gK + (size_t)c0 * 64, lK[buf] + j0 * 512);
    gload16(gK + (size_t)c0 * 64 + 512, lK[buf] + (j0 + 1) * 512);
    gload16(gV + c0, lV[buf] + j0 * 512);
    gload16(gV + c0 + 8192, lV[buf] + (j0 + 1) * 512);
  };

  auto compute = [&](const u16* lKc, const u16* lVc, int c0) {
#pragma unroll
    for (int kt = 0; kt < 4; ++kt) {
      const int key = kt * 16 + r16;
      const bf16x8 bk0 = *(const bf16x8*)(lKc + key * 64 + ((g ^ (key & 7)) * 8));
      const bf16x8 bk1 = *(const bf16x8*)(lKc + key * 64 + (((4 + g) ^ (key & 7)) * 8));
      f32x4 S = {};
      S = __builtin_amdgcn_mfma_f32_16x16x32_bf16(bk0, aq0, S, 0, 0, 0);  // S'[key][query]
      S = __builtin_amdgcn_mfma_f32_16x16x32_bf16(bk1, aq1, S, 0, 0, 0);
      float p[4];
#pragma unroll
      for (int r = 0; r < 4; ++r) p[r] = exp2f(S[r]);
      if (c0 == 0 && kt == 0) {
        const int q = row0 + r16;                // global query row of this lane's column
        const bool dropk0 = (q >= 1 && q <= 8);  // interact rows 1..8: keys >= 9 only
#pragma unroll
        for (int r = 0; r < 4; ++r) {
          const int k = 4 * g + r;
          const bool keep = (k >= 9) || (k == 0 && !dropk0);
          p[r] = keep ? p[r] : 0.f;
        }
      }
      u32x2 w;
      w[0] = pack_trunc(p[0], p[1]);
      w[1] = pack_trunc(p[2], p[3]);
      *(u32x2*)((char*)lPw + r16 * 144 + kt * 32 + g * 8) = w;
    }
#pragma unroll
    for (int m = 0; m < 2; ++m) {
      const bf16x8 ap = *(const bf16x8*)((char*)lPw + r16 * 144 + m * 64 + g * 16);
#pragma unroll
      for (int jt = 0; jt < 4; ++jt) {
        const int d = jt * 16 + r16;
        const bf16x8 bv = *(const bf16x8*)(lVc + d * 64 + (((m * 4 + g) ^ (d & 7)) * 8));
        oa[jt] = __builtin_amdgcn_mfma_f32_16x16x32_bf16(ap, bv, oa[jt], 0, 0, 0);
      }
      osum = __builtin_amdgcn_mfma_f32_16x16x32_bf16(ap, vones, osum, 0, 0, 0);
    }
  };

  // prologue: stage chunk 0 into buffer 0
  stage(0, 0);
  __syncthreads();

  for (int it = 0; it < 8; ++it) {
    const int c0 = it * 128;
    stage(c0 + 64, 1);            // prefetch odd chunk into buf1
    compute(lK[0], lV[0], c0);
    __syncthreads();              // buf1 ready; buf0 free
    if (it < 7) stage(c0 + 128, 0);  // prefetch next even chunk into buf0
    compute(lK[1], lV[1], c0 + 64);
    __syncthreads();              // buf0 ready; buf1 free
  }

  const int b = bh / 12, h = bh - b * 12;
#pragma unroll
  for (int r = 0; r < 4; ++r) {
    const int grow = row0 + 4 * g + r;
    const bool full = (grow >= 1 && grow <= 8);
    const float inv = 1.f / osum[r];  // denominator from the same truncated bf16 P
#pragma unroll
    for (int jt = 0; jt < 4; ++jt) {
      const int d = jt * 16 + r16;
      const float vi = oa[jt][r] * inv;
      const float vb = full ? vmean[bh * 64 + d] : vi;
      og[((size_t)(8192 + b * 1024 + grow)) * 768 + h * 64 + d] = f2bf(vb);
      if (grow <= 8)  // interact rows 0..8 (only the rt==0 block reaches here)
        og[((size_t)(16384 + b * 1024 + grow)) * 768 + h * 64 + d] = f2bf(vi);
    }
  }
}

// ---------------- small branches (E path only) ----------------
// queries = 64 rows/block over all 1024 rows, keys [0,16) masked k<9.
//   grow < 9 : head rows 0..8 (computed)
//   grow >= 9: interact rows>=9 (computed) + head rows>=9 (vmean fill)
__global__ __launch_bounds__(256) void smalls_attn(const u16* __restrict__ qg, const u16* __restrict__ kg,
                                                   const u16* __restrict__ vg, const float* __restrict__ vmean,
                                                   u16* __restrict__ og) {
  __shared__ __align__(16) u16 lP2[4][16 * 40];  // per-wave P[query][key 0..31], 80B stride
  __shared__ float lsRed[4][16];
  const int bh = blockIdx.y;
  const int b = bh / 12, h = bh - b * 12;
  const int tid = threadIdx.x, wid = tid >> 6, lane = tid & 63;
  const int g = lane >> 4, r16 = lane & 15;
  u16* lPw = lP2[wid];

  const int row0 = blockIdx.x * 64 + wid * 16;
  const u16* qrow = qg + ((size_t)bh * 1024 + row0 + r16) * 64;
  const bf16x8 aq0 = *(const bf16x8*)(qrow + g * 8);
  const bf16x8 aq1 = *(const bf16x8*)(qrow + 32 + g * 8);
  const u16* krow = kg + ((size_t)bh * 1024 + r16) * 64;  // keys 0..15
  const bf16x8 bk0 = *(const bf16x8*)(krow + g * 8);
  const bf16x8 bk1 = *(const bf16x8*)(krow + 32 + g * 8);
  f32x4 S = {};
  S = __builtin_amdgcn_mfma_f32_16x16x32_bf16(bk0, aq0, S, 0, 0, 0);  // S'[key][query]
  S = __builtin_amdgcn_mfma_f32_16x16x32_bf16(bk1, aq1, S, 0, 0, 0);
  float p[4];
  float lsum = 0.f;
#pragma unroll
  for (int r = 0; r < 4; ++r) {
    const int k = 4 * g + r;
    p[r] = (k < 9) ? exp2f(S[r]) : 0.f;
    lsum += p[r];
  }
  {
    u16x4 pk;
#pragma unroll
    for (int r = 0; r < 4; ++r) pk[r] = f2bf(p[r]);
    *(u16x4*)((char*)lPw + r16 * 80 + g * 8) = pk;
    u16x4 z = {0, 0, 0, 0};
    *(u16x4*)((char*)lPw + r16 * 80 + 32 + g * 8) = z;  // keys 16..31 = 0
  }
  lsum += __shfl_xor(lsum, 16);
  lsum += __shfl_xor(lsum, 32);
  if (lane < 16) lsRed[wid][lane] = lsum;
  const bf16x8 ap = *(const bf16x8*)((char*)lPw + r16 * 80 + g * 16);
  f32x4 oa[4] = {};
#pragma unroll
  for (int jt = 0; jt < 4; ++jt) {
    const u16* vrow = vg + ((size_t)bh * 64 + jt * 16 + r16) * 1024;  // tokens 0..31
    const bf16x8 bv = *(const bf16x8*)(vrow + g * 8);
    oa[jt] = __builtin_amdgcn_mfma_f32_16x16x32_bf16(ap, bv, oa[jt], 0, 0, 0);
  }
#pragma unroll
  for (int r = 0; r < 4; ++r) {
    const int grow = row0 + 4 * g + r;
    const float inv = 1.f / lsRed[wid][4 * g + r];
#pragma unroll
    for (int jt = 0; jt < 4; ++jt) {
      const int d = jt * 16 + r16;
      const float v = oa[jt][r] * inv;
      if (grow >= 9) {
        og[((size_t)(16384 + b * 1024 + grow)) * 768 + h * 64 + d] = f2bf(v);          // interact
        og[((size_t)(b * 1024 + grow)) * 768 + h * 64 + d] = f2bf(vmean[bh * 64 + d]); // head fill
      } else {
        og[((size_t)(b * 1024 + grow)) * 768 + h * 64 + d] = f2bf(v);                  // head 0..8
      }
    }
  }
}

// ---------------- host launcher ----------------
extern "C" void kernel_launch(void* const* d_in, const int* in_sizes, int n_in,
                              void* d_out, int out_size, void* d_ws, size_t ws_size,
                              hipStream_t stream) {
  (void)in_sizes; (void)n_in; (void)out_size; (void)ws_size;
  const float* x      = (const float*)d_in[0];
  const float* w_qkv  = (const float*)d_in[1];
  const float* w_proj = (const float*)d_in[2];
  const float* b_proj = (const float*)d_in[3];

  char* ws = (char*)d_ws;
  u16* xb     = (u16*)(ws + 0);
  u16* wqkvb  = (u16*)(ws + 12582912);
  u16* wprojb = (u16*)(ws + 16121856);
  u16* qb     = (u16*)(ws + 17301504);
  u16* kb     = (u16*)(ws + 29884416);
  u16* vTb    = (u16*)(ws + 42467328);
  float* vmn  = (float*)(ws + 55050240);
  u16* ob     = (u16*)(ws + 55074816);

  cvt3_kernel<<<8449, 256, 0, stream>>>(x, xb, 1572864, w_qkv, wqkvb, 442368, w_proj, wprojb, 147456);

  gemm_bt<0, 8192, 2304, 768><<<dim3(64, 18), 256, 0, stream>>>(
      xb, wqkvb, qb, kb, vTb, nullptr, nullptr);

  vmean_kernel<<<96, 256, 0, stream>>>(vTb, vmn);

  body_attn<<<1536, 256, 0, stream>>>(qb, kb, vTb, vmn, ob);
  smalls_attn<<<dim3(16, 96), 256, 0, stream>>>(qb, kb, vTb, vmn, ob);

  gemm_bt<1, 24576, 768, 768><<<dim3(192, 6), 256, 0, stream>>>(
      ob, wprojb, nullptr, nullptr, nullptr, (float*)d_out, b_proj);
}